// Round 3
// baseline (776.275 us; speedup 1.0000x reference)
//
#include <hip/hip_runtime.h>
#include <hip/hip_bf16.h>
#include <hip/hip_cooperative_groups.h>
#include <math.h>

namespace cg = cooperative_groups;

#define N_NODES   15000
#define N_EDGES   60000
#define EVOCAB    54
#define NODE_INDIM 64
#define EDGE_INDIM 32
#define H  32
#define EH 64
#define N_BOND 4

// Phase-A task ranges (flat lane-task index space)
#define TASK_VOCAB  (EVOCAB * 1024)                 // 55296  (one MLP output / thread)
#define TASK_PROJ   (N_NODES * H)                   // 480000 (one h element / thread)
#define TASK_ZERO   ((N_NODES * H + N_NODES) / 4)   // 123750 float4 stores (agg+sm contig)
#define TA (TASK_VOCAB + TASK_PROJ + TASK_ZERO)     // 659046

struct Params {
    const int *node_ids, *edge_ids, *src, *dst;
    const float *node_table, *edge_table, *proj_W, *proj_b, *attn_w;
    const float *e1_W1, *e1_b1, *e1_W2, *e1_b2;
    const float *e2_W1, *e2_b1, *e2_W2, *e2_b2;
    const float *gWih, *gWhh, *gbih, *gbhh;
    float *Wt;    // [54][32(o)][32(i)] transposed vocab weights
    float *h;     // [N][32]
    float *agg;   // [N][32]  (sm immediately follows -> one contiguous zero range)
    float *sm;    // [N]
    float *out;   // d_out
};

__launch_bounds__(256, 2)
__global__ void fused_mpnn(Params p) {
    cg::grid_group grid = cg::this_grid();
    const int tid = blockIdx.x * 256 + threadIdx.x;
    const int NT  = gridDim.x * 256;

    // ============================ Phase A ============================
    // (a) 54x32x32 vocab weight table  (b) h0 = relu(nf @ Wp.T + bp)
    // (c) zero agg+sm.  All independent -> one phase.
    for (int t = tid; t < TA; t += NT) {
        if (t < TASK_VOCAB) {
            int v = t >> 10, f = t & 1023, l = t & 63;   // wave-uniform v (1024%64==0)
            const float* W1 = (v < N_BOND) ? p.e1_W1 : p.e2_W1;
            const float* b1 = (v < N_BOND) ? p.e1_b1 : p.e2_b1;
            const float* W2 = (v < N_BOND) ? p.e1_W2 : p.e2_W2;
            const float* b2 = (v < N_BOND) ? p.e1_b2 : p.e2_b2;
            const float* ef = p.edge_table + v * EDGE_INDIM;
            // lane l computes z[l] (EH=64 == wave size)
            float z = b1[l];
            const float* w1r = W1 + l * EDGE_INDIM;
            #pragma unroll
            for (int j = 0; j < EDGE_INDIM; ++j) z += ef[j] * w1r[j];
            z = fmaxf(z, 0.f);
            // each lane: one output f, z broadcast via wave-wide shfl
            float y = b2[f];
            const float* w2r = W2 + f * EH;
            #pragma unroll
            for (int k = 0; k < EH; ++k) y += __shfl(z, k, 64) * w2r[k];
            // store transposed: f = i*32 + o  ->  Wt[v][o][i]
            p.Wt[v * 1024 + (f & 31) * 32 + (f >> 5)] = y;
        } else if (t < TASK_VOCAB + TASK_PROJ) {
            int q = t - TASK_VOCAB;
            int n = q >> 5, o = q & 31;
            int gid = p.node_ids[n];
            const float* nf = p.node_table + (size_t)gid * NODE_INDIM;
            const float* wr = p.proj_W + o * NODE_INDIM;   // hot, L1-resident
            float acc = p.proj_b[o];
            #pragma unroll 8
            for (int j = 0; j < NODE_INDIM; ++j) acc += nf[j] * wr[j];
            p.h[q] = fmaxf(acc, 0.f);
        } else {
            int q = t - TASK_VOCAB - TASK_PROJ;
            ((float4*)p.agg)[q] = make_float4(0.f, 0.f, 0.f, 0.f);
        }
    }
    grid.sync();

    // ============================ 3 MP steps ============================
    for (int step = 0; step < 3; ++step) {
        // ---- Phase C: fused attention + message scatter (32 lanes / edge)
        // alpha normalization deferred to Phase D: agg += ex*y, sm += ex.
        for (int t = tid; t < N_EDGES * 32; t += NT) {
            int e = t >> 5, o = t & 31;
            int s = p.src[e], d = p.dst[e], v = p.edge_ids[e];
            float hs = p.h[s * 32 + o];
            float hd = p.h[d * 32 + o];
            float val = hs * p.attn_w[o] + hd * p.attn_w[32 + o];
            #pragma unroll
            for (int k = 16; k > 0; k >>= 1) val += __shfl_xor(val, k, 32);
            float a  = (val > 0.f) ? val : 0.01f * val;   // leaky_relu(0.01)
            float ex = __expf(a);                          // e^a  (NOT exp2!)
            // y_o = sum_i h_s[i] * W[i][o]  (row o of transposed table, 128B)
            const float4* W4 = (const float4*)(p.Wt + v * 1024 + o * 32);
            float y = 0.f;
            #pragma unroll
            for (int ii = 0; ii < 8; ++ii) {
                float4 w = W4[ii];
                y += __shfl(hs, 4 * ii, 32)     * w.x;
                y += __shfl(hs, 4 * ii + 1, 32) * w.y;
                y += __shfl(hs, 4 * ii + 2, 32) * w.z;
                y += __shfl(hs, 4 * ii + 3, 32) * w.w;
            }
            atomicAdd(&p.agg[d * 32 + o], ex * y);
            if (o == 0) atomicAdd(&p.sm[d], ex);
        }
        grid.sync();

        // ---- Phase D: normalize + relu + GRU; re-zero agg/sm for next step
        float* hout = (step == 2) ? p.out : p.h;
        for (int t = tid; t < N_NODES * 32; t += NT) {
            int n = t >> 5, o = t & 31;
            float sinv = 1.f / p.sm[n];                 // broadcast load
            float m  = fmaxf(p.agg[t] * sinv, 0.f);
            float hv = p.h[t];
            float gir = 0.f, giz = 0.f, gin = 0.f, ghr = 0.f, ghz = 0.f, ghn = 0.f;
            const float* Wi0 = p.gWih + o * 32;         // rows o, 32+o, 64+o (L1-hot)
            const float* Wi1 = p.gWih + (32 + o) * 32;
            const float* Wi2 = p.gWih + (64 + o) * 32;
            const float* Wh0 = p.gWhh + o * 32;
            const float* Wh1 = p.gWhh + (32 + o) * 32;
            const float* Wh2 = p.gWhh + (64 + o) * 32;
            #pragma unroll 4
            for (int j = 0; j < 32; ++j) {
                float mj = __shfl(m, j, 32);
                float hj = __shfl(hv, j, 32);
                gir += mj * Wi0[j];  giz += mj * Wi1[j];  gin += mj * Wi2[j];
                ghr += hj * Wh0[j];  ghz += hj * Wh1[j];  ghn += hj * Wh2[j];
            }
            float r = 1.f / (1.f + __expf(-(gir + p.gbih[o]      + ghr + p.gbhh[o])));
            float z = 1.f / (1.f + __expf(-(giz + p.gbih[32 + o] + ghz + p.gbhh[32 + o])));
            float nn = tanhf(gin + p.gbih[64 + o] + r * (ghn + p.gbhh[64 + o]));
            hout[t] = (1.f - z) * nn + z * hv;
            p.agg[t] = 0.f;                              // re-zero for next step
            if (o == 0) p.sm[n] = 0.f;
        }
        grid.sync();
    }
}

extern "C" void kernel_launch(void* const* d_in, const int* in_sizes, int n_in,
                              void* d_out, int out_size, void* d_ws, size_t ws_size,
                              hipStream_t stream) {
    Params p;
    p.node_ids   = (const int*)d_in[0];
    p.edge_ids   = (const int*)d_in[1];
    p.src        = (const int*)d_in[2];
    p.dst        = (const int*)d_in[3];
    p.node_table = (const float*)d_in[4];
    p.edge_table = (const float*)d_in[5];
    p.proj_W     = (const float*)d_in[6];
    p.proj_b     = (const float*)d_in[7];
    p.attn_w     = (const float*)d_in[8];
    p.e1_W1 = (const float*)d_in[9];  p.e1_b1 = (const float*)d_in[10];
    p.e1_W2 = (const float*)d_in[11]; p.e1_b2 = (const float*)d_in[12];
    p.e2_W1 = (const float*)d_in[13]; p.e2_b1 = (const float*)d_in[14];
    p.e2_W2 = (const float*)d_in[15]; p.e2_b2 = (const float*)d_in[16];
    p.gWih  = (const float*)d_in[17]; p.gWhh  = (const float*)d_in[18];
    p.gbih  = (const float*)d_in[19]; p.gbhh  = (const float*)d_in[20];

    // workspace layout (16B-aligned): Wt | h | agg | sm   (agg,sm contiguous)
    char* ws = (char*)d_ws;
    p.Wt  = (float*)(ws);                               // 221184 B
    p.h   = (float*)(ws + 221184);                      // 1920000 B
    p.agg = (float*)(ws + 221184 + 1920000);            // 1920000 B
    p.sm  = (float*)(ws + 221184 + 1920000 + 1920000);  // 60000 B
    p.out = (float*)d_out;

    int maxb = 0;
    int nblk = 512;   // 2 blocks/CU target
    if (hipOccupancyMaxActiveBlocksPerMultiprocessor(&maxb, fused_mpnn, 256, 0) == hipSuccess
        && maxb >= 1) {
        int cap = maxb * 256;   // 256 CUs
        if (nblk > cap) nblk = cap;
    }
    void* kargs[] = { (void*)&p };
    hipLaunchCooperativeKernel((void*)fused_mpnn, dim3(nblk), dim3(256), kargs, 0, stream);
}

// Round 4
// 226.258 us; speedup vs baseline: 3.4309x; 3.4309x over previous
//
#include <hip/hip_runtime.h>
#include <hip/hip_bf16.h>
#include <math.h>

#define N_NODES   15000
#define N_EDGES   60000
#define EVOCAB    54
#define NODE_INDIM 64
#define EDGE_INDIM 32
#define H  32
#define EH 64
#define N_BOND 4

// setup task ranges (block-aligned: 55296/256=216, +480000 -> 2091 blocks exact)
#define TASK_VOCAB (EVOCAB * 1024)                  // 55296
#define TASK_PROJ  (N_NODES * H)                    // 480000
#define TASK_ZERO  ((N_NODES * H + N_NODES) / 4)    // 123750 float4 (agg+sm contiguous)
#define TASK_PACK  (3 * H * H)                      // 3072
#define TA (TASK_VOCAB + TASK_PROJ + TASK_ZERO + TASK_PACK)   // 662118

// ---------------------------------------------------------------------------
// Setup: (a) 54x32x32 vocab weight table [v][i][o]  (b) h0 projection
// (c) zero agg+sm  (d) pack GRU weights transposed for coalesced reads:
//     Wpk4[j*32+o] = {Wih[o][j], Wih[32+o][j], Wih[64+o][j], Whh[o][j]}
//     Wpk2[j*32+o] = {Whh[32+o][j], Whh[64+o][j]}
// ---------------------------------------------------------------------------
__global__ void setup_kernel(const int* __restrict__ node_ids,
                             const float* __restrict__ node_table,
                             const float* __restrict__ edge_table,
                             const float* __restrict__ proj_W, const float* __restrict__ proj_b,
                             const float* __restrict__ e1_W1, const float* __restrict__ e1_b1,
                             const float* __restrict__ e1_W2, const float* __restrict__ e1_b2,
                             const float* __restrict__ e2_W1, const float* __restrict__ e2_b1,
                             const float* __restrict__ e2_W2, const float* __restrict__ e2_b2,
                             const float* __restrict__ gWih, const float* __restrict__ gWhh,
                             float* __restrict__ Wt, float* __restrict__ h,
                             float* __restrict__ agg,
                             float4* __restrict__ Wpk4, float2* __restrict__ Wpk2) {
    int t = blockIdx.x * 256 + threadIdx.x;
    if (t >= TA) return;
    if (t < TASK_VOCAB) {
        int v = t >> 10, f = t & 1023, l = t & 63;   // v wave-uniform (1024 % 64 == 0)
        const float* W1 = (v < N_BOND) ? e1_W1 : e2_W1;
        const float* b1 = (v < N_BOND) ? e1_b1 : e2_b1;
        const float* W2 = (v < N_BOND) ? e1_W2 : e2_W2;
        const float* b2 = (v < N_BOND) ? e1_b2 : e2_b2;
        const float* ef = edge_table + v * EDGE_INDIM;
        // lane l computes z[l] (EH == wave size)
        float z = b1[l];
        const float* w1r = W1 + l * EDGE_INDIM;
        #pragma unroll
        for (int j = 0; j < EDGE_INDIM; ++j) z += ef[j] * w1r[j];
        z = fmaxf(z, 0.f);
        float y = b2[f];
        const float* w2r = W2 + f * EH;
        #pragma unroll
        for (int k = 0; k < EH; ++k) y += __shfl(z, k, 64) * w2r[k];
        Wt[v * 1024 + f] = y;                        // untransposed: f = i*32 + o
    } else if (t < TASK_VOCAB + TASK_PROJ) {
        int q = t - TASK_VOCAB;
        int n = q >> 5, o = q & 31;
        int gid = node_ids[n];
        const float* nf = node_table + (size_t)gid * NODE_INDIM;
        const float* wr = proj_W + o * NODE_INDIM;
        float acc = proj_b[o];
        #pragma unroll 8
        for (int j = 0; j < NODE_INDIM; ++j) acc += nf[j] * wr[j];
        h[q] = fmaxf(acc, 0.f);
    } else if (t < TASK_VOCAB + TASK_PROJ + TASK_ZERO) {
        int q = t - TASK_VOCAB - TASK_PROJ;
        ((float4*)agg)[q] = make_float4(0.f, 0.f, 0.f, 0.f);
    } else {
        int q = t - TASK_VOCAB - TASK_PROJ - TASK_ZERO;   // q = j*32 + o
        int j = q >> 5, o = q & 31;
        Wpk4[q] = make_float4(gWih[o * 32 + j], gWih[(32 + o) * 32 + j],
                              gWih[(64 + o) * 32 + j], gWhh[o * 32 + j]);
        Wpk2[q] = make_float2(gWhh[(32 + o) * 32 + j], gWhh[(64 + o) * 32 + j]);
    }
}

// ---------------------------------------------------------------------------
// Edge pass: attention logit + unnormalized message scatter.
// 32 lanes/edge; W reads coalesced (lanes o consecutive); normalization by
// sm deferred to the GRU kernel.
// ---------------------------------------------------------------------------
__launch_bounds__(256)
__global__ void edge_kernel(const int* __restrict__ src, const int* __restrict__ dst,
                            const int* __restrict__ edge_ids,
                            const float* __restrict__ h, const float* __restrict__ Wt,
                            const float* __restrict__ attn_w,
                            float* __restrict__ agg, float* __restrict__ sm) {
    int t = blockIdx.x * 256 + threadIdx.x;
    int e = t >> 5, o = t & 31;
    int s = src[e], d = dst[e], v = edge_ids[e];
    float hs = h[s * 32 + o];
    float val = hs * attn_w[o] + h[d * 32 + o] * attn_w[32 + o];
    #pragma unroll
    for (int k = 16; k > 0; k >>= 1) val += __shfl_xor(val, k, 32);
    float a  = (val > 0.f) ? val : 0.01f * val;    // leaky_relu slope 0.01
    float ex = __expf(a);
    const float* W = Wt + v * 1024 + o;            // column o, rows i*32 apart
    float y = 0.f;
    #pragma unroll
    for (int i = 0; i < 32; ++i)
        y += __shfl(hs, i, 32) * W[i * 32];        // coalesced across lanes
    atomicAdd(&agg[d * 32 + o], ex * y);
    if (o == 0) atomicAdd(&sm[d], ex);
}

// ---------------------------------------------------------------------------
// GRU: normalize + relu + GRU cell; re-zero agg/sm for the next step.
// Packed-transposed weights -> every load is wave-coalesced/broadcast.
// ---------------------------------------------------------------------------
__launch_bounds__(256)
__global__ void gru_kernel(float* __restrict__ agg, float* __restrict__ sm,
                           const float* __restrict__ h,
                           const float4* __restrict__ Wpk4, const float2* __restrict__ Wpk2,
                           const float* __restrict__ gbih, const float* __restrict__ gbhh,
                           float* __restrict__ hout) {
    int t = blockIdx.x * 256 + threadIdx.x;        // t < 480000
    int n = t >> 5, o = t & 31;
    float sinv = 1.f / sm[n];
    float m  = fmaxf(agg[t] * sinv, 0.f);
    float hv = h[t];
    float gir = 0.f, giz = 0.f, gin = 0.f, ghr = 0.f, ghz = 0.f, ghn = 0.f;
    #pragma unroll 8
    for (int j = 0; j < 32; ++j) {
        float mj = __shfl(m, j, 32);
        float hj = __shfl(hv, j, 32);
        float4 a = Wpk4[j * 32 + o];               // lanes contiguous 512B, broadcast
        float2 b = Wpk2[j * 32 + o];
        gir += mj * a.x;  giz += mj * a.y;  gin += mj * a.z;
        ghr += hj * a.w;  ghz += hj * b.x;  ghn += hj * b.y;
    }
    float r  = 1.f / (1.f + __expf(-(gir + gbih[o]      + ghr + gbhh[o])));
    float z  = 1.f / (1.f + __expf(-(giz + gbih[32 + o] + ghz + gbhh[32 + o])));
    float nn = tanhf(gin + gbih[64 + o] + r * (ghn + gbhh[64 + o]));
    hout[t] = (1.f - z) * nn + z * hv;
    agg[t] = 0.f;                                  // ready for next step
    if (o == 0) sm[n] = 0.f;
}

// ---------------------------------------------------------------------------
extern "C" void kernel_launch(void* const* d_in, const int* in_sizes, int n_in,
                              void* d_out, int out_size, void* d_ws, size_t ws_size,
                              hipStream_t stream) {
    const int*   node_ids   = (const int*)d_in[0];
    const int*   edge_ids   = (const int*)d_in[1];
    const int*   src        = (const int*)d_in[2];
    const int*   dst        = (const int*)d_in[3];
    const float* node_table = (const float*)d_in[4];
    const float* edge_table = (const float*)d_in[5];
    const float* proj_W     = (const float*)d_in[6];
    const float* proj_b     = (const float*)d_in[7];
    const float* attn_w     = (const float*)d_in[8];
    const float* e1_W1 = (const float*)d_in[9];  const float* e1_b1 = (const float*)d_in[10];
    const float* e1_W2 = (const float*)d_in[11]; const float* e1_b2 = (const float*)d_in[12];
    const float* e2_W1 = (const float*)d_in[13]; const float* e2_b1 = (const float*)d_in[14];
    const float* e2_W2 = (const float*)d_in[15]; const float* e2_b2 = (const float*)d_in[16];
    const float* gWih  = (const float*)d_in[17]; const float* gWhh  = (const float*)d_in[18];
    const float* gbih  = (const float*)d_in[19]; const float* gbhh  = (const float*)d_in[20];

    // workspace: Wt | h | agg | sm (contig w/ agg) | Wpk4 | Wpk2   (~4.3 MB)
    char* ws = (char*)d_ws;
    float*  Wt   = (float*)(ws);                               // 221184 B
    float*  h    = (float*)(ws + 221184);                      // 1920000 B
    float*  agg  = (float*)(ws + 221184 + 1920000);            // 1920000 B
    float*  sm   = (float*)(ws + 221184 + 3840000);            // 60000 B
    float4* Wpk4 = (float4*)(ws + 221184 + 3840000 + 60000);   // 49152 B
    float2* Wpk2 = (float2*)(ws + 221184 + 3840000 + 60000 + 49152); // 24576 B
    float*  out  = (float*)d_out;

    setup_kernel<<<(TA + 255) / 256, 256, 0, stream>>>(
        node_ids, node_table, edge_table, proj_W, proj_b,
        e1_W1, e1_b1, e1_W2, e1_b2, e2_W1, e2_b1, e2_W2, e2_b2,
        gWih, gWhh, Wt, h, agg, Wpk4, Wpk2);

    for (int step = 0; step < 3; ++step) {
        edge_kernel<<<(N_EDGES * 32) / 256, 256, 0, stream>>>(
            src, dst, edge_ids, h, Wt, attn_w, agg, sm);
        float* hout = (step == 2) ? out : h;
        gru_kernel<<<(N_NODES * 32) / 256, 256, 0, stream>>>(
            agg, sm, h, Wpk4, Wpk2, gbih, gbhh, hout);
    }
}